// Round 16
// baseline (3204.806 us; speedup 1.0000x reference)
//
#include <hip/hip_runtime.h>

typedef _Float16 f16;
typedef _Float16 f16x8 __attribute__((ext_vector_type(8)));
typedef float f32x4 __attribute__((ext_vector_type(4)));
typedef unsigned long long u64;

#define B_ 64
#define S_ 1024
#define E_ 256
#define H_ 512
#define NG 1536         // 3*H packed gate rows (r | z | n)
#define V_ 50257
#define TCH 128         // timesteps per chunk
#define NCHUNK (S_/TCH)
#define ROWS_CH (TCH*B_)   // 8192
#define HS_LD 544       // 1088B rows: quad-bank = 4*bq + j4 -> all 32 lane-groups distinct

__device__ __forceinline__ float sigm(float x) { return 1.f / (1.f + __expf(-x)); }

#define ALOAD(p) __hip_atomic_load((p), __ATOMIC_RELAXED, __HIP_MEMORY_SCOPE_AGENT)
#define ASTORE(p, v) __hip_atomic_store((p), (v), __ATOMIC_RELAXED, __HIP_MEMORY_SCOPE_AGENT)

// ------------------------- emb fp32 -> fp16 (one-time) -------------------------
__global__ __launch_bounds__(256) void k_embconv(const float* __restrict__ emb,
        f16* __restrict__ out) {
    long long i = (long long)blockIdx.x * 256 + threadIdx.x;
    if (i >= (long long)V_ * E_ / 4) return;
    float4 v = reinterpret_cast<const float4*>(emb)[i];
    union { f16 h[4]; u64 u; } w;
    w.h[0] = (f16)v.x; w.h[1] = (f16)v.y; w.h[2] = (f16)v.z; w.h[3] = (f16)v.w;
    reinterpret_cast<u64*>(out)[i] = w.u;
}

// ------------- pack [gate_w slice ; gi_or_gh_w] into fp16 [1536][KK] -------------
__global__ __launch_bounds__(256) void k_packW(const float* __restrict__ gw, int ld, int off,
        const float* __restrict__ g2, f16* __restrict__ W, int KK) {
    int idx = blockIdx.x * 256 + threadIdx.x;
    int per = KK >> 2;
    if (idx >= NG * per) return;
    int row = idx / per;
    int c4 = (idx % per) << 2;
    const float* src = (row < 1024) ? gw + (size_t)row * ld + off + c4
                                    : g2 + (size_t)(row - 1024) * KK + c4;
    float4 v = *reinterpret_cast<const float4*>(src);
    union { f16 h[4]; u64 u; } w;
    w.h[0] = (f16)v.x; w.h[1] = (f16)v.y; w.h[2] = (f16)v.z; w.h[3] = (f16)v.w;
    *reinterpret_cast<u64*>(W + (size_t)row * KK + c4) = w.u;
}

__global__ __launch_bounds__(256) void k_packBias(const float* __restrict__ gb,
        const float* __restrict__ gib, float* __restrict__ bias) {
    int i = blockIdx.x * 256 + threadIdx.x;
    if (i < 1024) bias[i] = gb[i];
    else if (i < NG) bias[i] = gib[i - 1024];
}

// --------- GEMM: C[M,1536] = A[M,K] * Bm[1536,K]^T + bias ; fp16 in/out, fp32 acc ---------
__global__ __launch_bounds__(256) void k_gemm(const f16* __restrict__ A,
        const f16* __restrict__ Bm, const float* __restrict__ bias,
        f16* __restrict__ C, int K) {
    __shared__ f16 As[64][40];
    __shared__ f16 Bs[64][40];
    const int tid = threadIdx.x;
    const int m0 = blockIdx.y << 6, n0 = blockIdx.x << 6;
    const int w = tid >> 6, l = tid & 63;
    const int wr = (w >> 1) << 5, wc = (w & 1) << 5;
    const int srow = tid >> 2, sc8 = (tid & 3) << 3;
    const int fr = l & 15, kl = (l >> 4) << 3;
    f32x4 acc[2][2] = {};
    for (int k0 = 0; k0 < K; k0 += 32) {
        *reinterpret_cast<f16x8*>(&As[srow][sc8]) =
            *reinterpret_cast<const f16x8*>(A + (size_t)(m0 + srow) * K + k0 + sc8);
        *reinterpret_cast<f16x8*>(&Bs[srow][sc8]) =
            *reinterpret_cast<const f16x8*>(Bm + (size_t)(n0 + srow) * K + k0 + sc8);
        __syncthreads();
        f16x8 a0 = *reinterpret_cast<const f16x8*>(&As[wr + fr][kl]);
        f16x8 a1 = *reinterpret_cast<const f16x8*>(&As[wr + 16 + fr][kl]);
        f16x8 b0 = *reinterpret_cast<const f16x8*>(&Bs[wc + fr][kl]);
        f16x8 b1 = *reinterpret_cast<const f16x8*>(&Bs[wc + 16 + fr][kl]);
        acc[0][0] = __builtin_amdgcn_mfma_f32_16x16x32_f16(a0, b0, acc[0][0], 0, 0, 0);
        acc[0][1] = __builtin_amdgcn_mfma_f32_16x16x32_f16(a0, b1, acc[0][1], 0, 0, 0);
        acc[1][0] = __builtin_amdgcn_mfma_f32_16x16x32_f16(a1, b0, acc[1][0], 0, 0, 0);
        acc[1][1] = __builtin_amdgcn_mfma_f32_16x16x32_f16(a1, b1, acc[1][1], 0, 0, 0);
        __syncthreads();
    }
    for (int fm = 0; fm < 2; ++fm)
        for (int fn = 0; fn < 2; ++fn) {
            int col = n0 + wc + (fn << 4) + fr;
            float bv = bias[col];
            for (int j = 0; j < 4; ++j) {
                int rowg = m0 + wr + (fm << 4) + ((l >> 4) << 2) + j;
                C[(size_t)rowg * NG + col] = (f16)(acc[fm][fn][j] + bv);
            }
        }
}

// --- GEMM with fused embedding gather: A[m][k] = embh[tok[b(m)]][k], K = E_ = 256 ---
__global__ __launch_bounds__(256) void k_gemmE(const int* __restrict__ tok, int t0,
        const f16* __restrict__ embh, const f16* __restrict__ Bm,
        const float* __restrict__ bias, f16* __restrict__ C) {
    __shared__ f16 As[64][40];
    __shared__ f16 Bs[64][40];
    const int tid = threadIdx.x;
    const int m0 = blockIdx.y << 6, n0 = blockIdx.x << 6;
    const int w = tid >> 6, l = tid & 63;
    const int wr = (w >> 1) << 5, wc = (w & 1) << 5;
    const int srow = tid >> 2, sc8 = (tid & 3) << 3;
    const int fr = l & 15, kl = (l >> 4) << 3;
    // row -> token (rows ordered (t, b): r>>6 = chunk-local t, r&63 = b)
    const int grow = m0 + srow;
    const int tk = tok[(grow & 63) * S_ + t0 + (grow >> 6)];
    const f16* arow = embh + (size_t)tk * E_;
    f32x4 acc[2][2] = {};
    for (int k0 = 0; k0 < E_; k0 += 32) {
        *reinterpret_cast<f16x8*>(&As[srow][sc8]) =
            *reinterpret_cast<const f16x8*>(arow + k0 + sc8);
        *reinterpret_cast<f16x8*>(&Bs[srow][sc8]) =
            *reinterpret_cast<const f16x8*>(Bm + (size_t)(n0 + srow) * E_ + k0 + sc8);
        __syncthreads();
        f16x8 a0 = *reinterpret_cast<const f16x8*>(&As[wr + fr][kl]);
        f16x8 a1 = *reinterpret_cast<const f16x8*>(&As[wr + 16 + fr][kl]);
        f16x8 b0 = *reinterpret_cast<const f16x8*>(&Bs[wc + fr][kl]);
        f16x8 b1 = *reinterpret_cast<const f16x8*>(&Bs[wc + 16 + fr][kl]);
        acc[0][0] = __builtin_amdgcn_mfma_f32_16x16x32_f16(a0, b0, acc[0][0], 0, 0, 0);
        acc[0][1] = __builtin_amdgcn_mfma_f32_16x16x32_f16(a0, b1, acc[0][1], 0, 0, 0);
        acc[1][0] = __builtin_amdgcn_mfma_f32_16x16x32_f16(a1, b0, acc[1][0], 0, 0, 0);
        acc[1][1] = __builtin_amdgcn_mfma_f32_16x16x32_f16(a1, b1, acc[1][1], 0, 0, 0);
        __syncthreads();
    }
    for (int fm = 0; fm < 2; ++fm)
        for (int fn = 0; fn < 2; ++fn) {
            int col = n0 + wc + (fn << 4) + fr;
            float bv = bias[col];
            for (int j = 0; j < 4; ++j) {
                int rowg = m0 + wr + (fm << 4) + ((l >> 4) << 2) + j;
                C[(size_t)rowg * NG + col] = (f16)(acc[fm][fn][j] + bv);
            }
        }
}

// --------------------------- persistent GRU recurrence, MFMA, tag-granule sync ---------------------------
// R15 verbatim except ONE isolated change: hx is double-buffered and the trailing
// __syncthreads (hx-reuse guard) is removed -> 2 barriers/step. Safe because:
// publish(s) reads hx[p]; gate(s+1) writes hx[p^1]; barrier1(s+1) orders all waves
// past publish-issue before any gate(s+1); MFMA(s) reads of HS complete before
// barrier2(s), and stage(s+1) writes HS only after barrier2(s).
__global__ __launch_bounds__(256, 1) void k_recur4(
        const f16* __restrict__ Wh0p, const f16* __restrict__ Wh1p,
        const f16* __restrict__ Z0, const f16* __restrict__ Z1,
        const float* __restrict__ ghb0, const float* __restrict__ ghb1,
        u64* ring0, u64* ring1, f16* __restrict__ H0out, f16* __restrict__ h1out,
        int t00, int n0, int t01, int n1) {
    __shared__ __align__(16) f16 HS[8][HS_LD];    // staged h(s), plain row-major
    __shared__ __align__(16) f16 hx[2][8][40];    // double-buffered gathered h_next
    const int blk = blockIdx.x;
    const int c = blk & 7;
    const int l = (blk >> 3) & 1;
    const int gg = blk >> 4;                      // 0..15
    const int nsteps = l ? n1 : n0;
    if (nsteps <= 0) return;
    const int t0 = l ? t01 : t00;
    const f16* __restrict__ Wh = l ? Wh1p : Wh0p;
    const f16* __restrict__ Z  = l ? Z1 : Z0;
    const float* __restrict__ ghb = l ? ghb1 : ghb0;
    u64* ring = l ? ring1 : ring0;                // [4 slots][8 clusters][2048 granules]

    const int i0 = gg << 5;                       // WG's first output
    const int tid = threadIdx.x;
    const int w = tid >> 6;                       // wave -> outputs i0+8w..+8w+7
    const int lane = tid & 63;
    const int colb = lane & 15;                   // C/D col (batch slot; 8-15 dup)
    const int bq = lane & 7;                      // real batch within cluster
    const int j4 = lane >> 4;                     // k-octet for A/B frags; out-group for C/D
    const int rrow = lane & 15;
    const int ol = rrow >> 2, gate = rrow & 3;    // A-row decode: row = ol*4 + gate (3=pad)

    // ---- preload recurrent weights into registers (constant all steps) ----
    f16x8 wA[2][16];
    #pragma unroll
    for (int tl = 0; tl < 2; ++tl) {
        const int out = i0 + (w << 3) + (tl << 2) + ol;
        #pragma unroll
        for (int t = 0; t < 16; ++t) {
            f16x8 v{};
            if (gate < 3)
                v = *reinterpret_cast<const f16x8*>(
                        Wh + ((size_t)(gate * H_ + out)) * H_ + (t << 5) + (j4 << 3));
            wA[tl][t] = v;
        }
    }
    const int outA = i0 + (w << 3) + j4;          // tile 0 gate-math output
    const int outB = outA + 4;                    // tile 1
    const float gbA = ghb[outA], gbB = ghb[outB];

    for (int sl = 0; sl < nsteps; ++sl) {
        const int s = t0 + sl;
        const int p = sl & 1;
        // ---- Z prefetch (independent of h; hides under stage retry) ----
        const size_t zrow = ((size_t)sl * 64 + (c << 3) + bq) * NG;
        float zrA = (float)Z[zrow + outA];
        float zzA = (float)Z[zrow + H_ + outA];
        float znA = (float)Z[zrow + 2 * H_ + outA];
        float zrB = (float)Z[zrow + outB];
        float zzB = (float)Z[zrow + H_ + outB];
        float znB = (float)Z[zrow + 2 * H_ + outB];
        // ---- stage h(s): 8 tagged granules/thread, BATCHED miss-mask retry ----
        {
            const u64* src = ring + ((size_t)(s & 3) * 8 + c) * 2048;
            u64 g[8];
            #pragma unroll
            for (int i = 0; i < 8; ++i) g[i] = ALOAD(src + (i << 8) + tid);
            unsigned miss = 0;
            #pragma unroll
            for (int i = 0; i < 8; ++i) {
                if ((unsigned)(g[i] >> 32) == (unsigned)s) {
                    *reinterpret_cast<unsigned*>(
                        &HS[i][((tid >> 4) << 5) + ((tid & 15) << 1)]) = (unsigned)g[i];
                } else miss |= 1u << i;
            }
            while (miss) {
                #pragma unroll
                for (int i = 0; i < 8; ++i)
                    if (miss & (1u << i)) g[i] = ALOAD(src + (i << 8) + tid);
                #pragma unroll
                for (int i = 0; i < 8; ++i)
                    if ((miss & (1u << i)) && (unsigned)(g[i] >> 32) == (unsigned)s) {
                        *reinterpret_cast<unsigned*>(
                            &HS[i][((tid >> 4) << 5) + ((tid & 15) << 1)]) = (unsigned)g[i];
                        miss &= ~(1u << i);
                    }
            }
        }
        __syncthreads();                          // barrier 1: HS ready
        // ---- MFMA: 2 tiles x K=512 (16 k-steps), B-frag shared across tiles ----
        f32x4 a00{}, a01{}, a10{}, a11{};
        #pragma unroll
        for (int t = 0; t < 16; ++t) {
            f16x8 bf = *reinterpret_cast<const f16x8*>(&HS[bq][(t << 5) + (j4 << 3)]);
            if (t & 1) {
                a01 = __builtin_amdgcn_mfma_f32_16x16x32_f16(wA[0][t], bf, a01, 0, 0, 0);
                a11 = __builtin_amdgcn_mfma_f32_16x16x32_f16(wA[1][t], bf, a11, 0, 0, 0);
            } else {
                a00 = __builtin_amdgcn_mfma_f32_16x16x32_f16(wA[0][t], bf, a00, 0, 0, 0);
                a10 = __builtin_amdgcn_mfma_f32_16x16x32_f16(wA[1][t], bf, a10, 0, 0, 0);
            }
        }
        f32x4 dA = a00 + a01;                     // rows: outA {r, z, n_h, pad}
        f32x4 dB = a10 + a11;                     // rows: outB
        // ---- gate math, in-lane; only cols 0-7 real ----
        if (colb < 8) {
            float holdA = (float)HS[bq][outA];
            float holdB = (float)HS[bq][outB];
            float rA = sigm(zrA + dA[0]);
            float zA = sigm(zzA + dA[1]);
            float nA = tanhf(znA + rA * (dA[2] + gbA));
            float rB = sigm(zrB + dB[0]);
            float zB = sigm(zzB + dB[1]);
            float nB = tanhf(znB + rB * (dB[2] + gbB));
            hx[p][bq][(w << 3) + j4]     = (f16)((1.f - zA) * nA + zA * holdA);
            hx[p][bq][(w << 3) + 4 + j4] = (f16)((1.f - zB) * nB + zB * holdB);
        }
        __syncthreads();                          // barrier 2: hx[p] ready
        // ---- publish h(s+1) as tagged granules (no drain, no flags) ----
        if (tid < 128) {
            const int b = tid >> 4, d = tid & 15;
            unsigned dval = *reinterpret_cast<const unsigned*>(&hx[p][b][d << 1]);
            u64 gr = ((u64)(unsigned)(s + 1) << 32) | (u64)dval;
            ASTORE(ring + ((size_t)((s + 1) & 3) * 8 + c) * 2048
                        + ((size_t)b << 8) + (gg << 4) + d, gr);
            if (l == 0)
                *reinterpret_cast<unsigned*>(
                    &H0out[((size_t)sl * 64 + (c << 3) + b) * H_ + i0 + (d << 1)]) = dval;
            else if (s == S_ - 1)
                *reinterpret_cast<unsigned*>(
                    &h1out[((size_t)(c << 3) + b) * H_ + i0 + (d << 1)]) = dval;
        }
        // no trailing barrier: hx is double-buffered; next stage writes HS only
        // after barrier 1 of the next iteration... (writes occur pre-barrier but
        // all MFMA reads of HS completed before this wave passed barrier 2)
    }
}

// ------------------------------- final head -------------------------------
__global__ __launch_bounds__(64) void k_final(const f16* __restrict__ h,
        const float* __restrict__ fcw, const float* __restrict__ fcb,
        float* __restrict__ out) {
    int b = threadIdx.x;
    float acc = fcb[0];
    for (int k = 0; k < H_; ++k) acc += (float)h[(size_t)b * H_ + k] * fcw[k];
    out[b] = sigm(acc);
}

extern "C" void kernel_launch(void* const* d_in, const int* in_sizes, int n_in,
                              void* d_out, int out_size, void* d_ws, size_t ws_size,
                              hipStream_t stream) {
    (void)in_sizes; (void)n_in; (void)out_size; (void)ws_size;
    const int*   tokens = (const int*)d_in[0];
    const float* emb  = (const float*)d_in[1];
    const float* fc_w = (const float*)d_in[2];
    const float* fc_b = (const float*)d_in[3];
    const float* gw0  = (const float*)d_in[4];
    const float* gb0  = (const float*)d_in[5];
    const float* giw0 = (const float*)d_in[6];
    const float* gib0 = (const float*)d_in[7];
    const float* ghw0 = (const float*)d_in[8];
    const float* ghb0 = (const float*)d_in[9];
    const float* gw1  = (const float*)d_in[10];
    const float* gb1  = (const float*)d_in[11];
    const float* giw1 = (const float*)d_in[12];
    const float* gib1 = (const float*)d_in[13];
    const float* ghw1 = (const float*)d_in[14];
    const float* ghb1 = (const float*)d_in[15];

    char* base = (char*)d_ws;
    size_t off = 0;
    auto carve = [&](size_t bytes) {
        char* p = base + off;
        off = (off + bytes + 255) & ~(size_t)255;
        return p;
    };
    f16*   embh  = (f16*)carve((size_t)V_ * E_ * 2);          // ~25.7 MB
    f16*   Wx0   = (f16*)carve((size_t)NG * 256 * 2);
    f16*   Wh0   = (f16*)carve((size_t)NG * 512 * 2);
    f16*   Wx1   = (f16*)carve((size_t)NG * 512 * 2);
    f16*   Wh1   = (f16*)carve((size_t)NG * 512 * 2);
    float* bias0 = (float*)carve(NG * 4);
    float* bias1 = (float*)carve(NG * 4);
    u64*   ring0 = (u64*)carve((size_t)4 * 8 * 2048 * 8);     // 512 KB
    u64*   ring1 = (u64*)carve((size_t)4 * 8 * 2048 * 8);     // 512 KB
    f16*   h1out = (f16*)carve((size_t)B_ * H_ * 2);
    f16*   Zc0   = (f16*)carve((size_t)ROWS_CH * NG * 2);
    f16*   H0c   = (f16*)carve((size_t)ROWS_CH * 512 * 2);
    f16*   Zc1   = (f16*)carve((size_t)ROWS_CH * NG * 2);

    hipMemsetAsync(ring0, 0, (size_t)4 * 8 * 2048 * 8, stream);
    hipMemsetAsync(ring1, 0, (size_t)4 * 8 * 2048 * 8, stream);

    k_embconv<<<(V_ * E_ / 4 + 255) / 256, 256, 0, stream>>>(emb, embh);
    k_packW<<<384, 256, 0, stream>>>(gw0, 768, 0,    giw0, Wx0, 256);
    k_packW<<<768, 256, 0, stream>>>(gw0, 768, 256,  ghw0, Wh0, 512);
    k_packW<<<768, 256, 0, stream>>>(gw1, 1024, 0,   giw1, Wx1, 512);
    k_packW<<<768, 256, 0, stream>>>(gw1, 1024, 512, ghw1, Wh1, 512);
    k_packBias<<<6, 256, 0, stream>>>(gb0, gib0, bias0);
    k_packBias<<<6, 256, 0, stream>>>(gb1, gib1, bias1);

    dim3 gemmGrid(NG / 64, ROWS_CH / 64);   // (24, 128)
    for (int ch = 0; ch < NCHUNK; ++ch) {
        int t0 = ch * TCH;
        k_gemmE<<<gemmGrid, 256, 0, stream>>>(tokens, t0, embh, Wx0, bias0, Zc0);
        // L0 of chunk ch runs concurrently with L1 of chunk ch-1
        k_recur4<<<256, 256, 0, stream>>>(Wh0, Wh1, Zc0, Zc1, ghb0, ghb1,
                                          ring0, ring1, H0c, h1out,
                                          t0, TCH, t0 - TCH, ch ? TCH : 0);
        k_gemm<<<gemmGrid, 256, 0, stream>>>(H0c, Wx1, bias1, Zc1, 512);
    }
    // drain: last chunk of layer 1
    k_recur4<<<256, 256, 0, stream>>>(Wh0, Wh1, Zc0, Zc1, ghb0, ghb1,
                                      ring0, ring1, H0c, h1out,
                                      0, 0, (NCHUNK - 1) * TCH, TCH);
    k_final<<<1, 64, 0, stream>>>(h1out, fc_w, fc_b, (float*)d_out);
}